// Round 1
// baseline (494.229 us; speedup 1.0000x reference)
//
#include <hip/hip_runtime.h>

#define BATCH 16384
#define N1 (BATCH * 196)   // layer1 elements
#define N2 (BATCH * 49)    // layer2 elements
#define EPSF 1e-5f

// ws layout (bytes):
//   [0,32)        : double stats[4] = {sum1, sumsq1, sum2, sumsq2}
//   [64, 115312)  : wt12 = w_fc2 transposed+padded: [2401][12] floats
//   [115312, ..)  : l1buf: BATCH*196 floats (12,845,056 B)
//   [12960368,..) : l2buf: BATCH*49 floats  (3,211,264 B)
#define WS_WT12_OFF   64
#define WS_L1_OFF     115312
#define WS_L2_OFF     12960368

__device__ __forceinline__ float tdot(float b00, float b01, float b10, float b11,
                                      const float* __restrict__ w) {
    float s = b00 * b00 * w[0];
    s += b01 * b01 * w[1];
    s += b10 * b10 * w[2];
    s += b11 * b11 * w[3];
    s += b00 * b01 * w[4];
    s += b00 * b10 * w[5];
    s += b00 * b11 * w[6];
    s += b01 * b10 * w[7];
    s += b01 * b11 * w[8];
    s += b10 * b11 * w[9];
    return s;
}

// block-level sum/sumsq reduction -> double atomics into stats[idx], stats[idx+1]
__device__ __forceinline__ void block_stats(float val, double* stats, int idx,
                                            float* wls, float* wlss) {
    float s = val, ss = val * val;
    #pragma unroll
    for (int off = 32; off; off >>= 1) {
        s += __shfl_down(s, off);
        ss += __shfl_down(ss, off);
    }
    int lane = threadIdx.x & 63, wid = threadIdx.x >> 6;
    if (lane == 0) { wls[wid] = s; wlss[wid] = ss; }
    __syncthreads();
    if (threadIdx.x == 0) {
        float S = wls[0] + wls[1] + wls[2] + wls[3];
        float SS = wlss[0] + wlss[1] + wlss[2] + wlss[3];
        atomicAdd(&stats[idx], (double)S);
        atomicAdd(&stats[idx + 1], (double)SS);
    }
}

// transpose w_fc2 (10 x 2401) -> wt12 (2401 x 12, last 2 cols zero-padded)
__global__ void __launch_bounds__(256) ktranspose(const float* __restrict__ wf2,
                                                  float* __restrict__ wt12) {
    int i = blockIdx.x * 256 + threadIdx.x;
    if (i >= 2401) return;
    #pragma unroll
    for (int o = 0; o < 10; ++o) wt12[i * 12 + o] = wf2[o * 2401 + i];
    wt12[i * 12 + 10] = 0.f;
    wt12[i * 12 + 11] = 0.f;
}

// Layer 1: one thread per (sample, 14x14 position). Writes l1, accumulates BN stats.
__global__ void __launch_bounds__(256) k1(const float* __restrict__ x,
                                          const float* __restrict__ w1,
                                          const float* __restrict__ wA,  // left_right
                                          const float* __restrict__ wB,  // top_bottom
                                          const float* __restrict__ wC,  // all
                                          const float* __restrict__ wD,  // none
                                          const float* __restrict__ w3,
                                          float* __restrict__ l1out,
                                          double* __restrict__ stats) {
    __shared__ float wls[4], wlss[4];
    int gid = blockIdx.x * 256 + threadIdx.x;
    int b = gid / 196;
    int pos = gid - b * 196;
    int i = pos / 14;
    int j = pos - i * 14;

    const float* xb = x + b * 784;
    int r0 = (2 * i) * 28 + 2 * j;
    float2 tp = *(const float2*)(xb + r0);
    float2 bo = *(const float2*)(xb + r0 + 28);
    float b00 = tp.x, b01 = tp.y, b10 = bo.x, b11 = bo.y;

    // weighted 2x2 pool
    float acc = b00 * w1[r0] + b01 * w1[r0 + 1] + b10 * w1[r0 + 28] + b11 * w1[r0 + 29];

    int wo = i * 140 + 10 * j;
    // left_right: zero col0 (b00,b10 at j==0), col27 (b01,b11 at j==13)
    {
        float m00 = (j == 0) ? 0.f : b00, m10 = (j == 0) ? 0.f : b10;
        float m01 = (j == 13) ? 0.f : b01, m11 = (j == 13) ? 0.f : b11;
        acc += tdot(m00, m01, m10, m11, wA + wo);
    }
    // top_bottom: zero row0 (b00,b01 at i==0), row27 (b10,b11 at i==13)
    {
        float m00 = (i == 0) ? 0.f : b00, m01 = (i == 0) ? 0.f : b01;
        float m10 = (i == 13) ? 0.f : b10, m11 = (i == 13) ? 0.f : b11;
        acc += tdot(m00, m01, m10, m11, wB + wo);
    }
    // all: both masks
    {
        float m00 = (i == 0 || j == 0) ? 0.f : b00;
        float m01 = (i == 0 || j == 13) ? 0.f : b01;
        float m10 = (i == 13 || j == 0) ? 0.f : b10;
        float m11 = (i == 13 || j == 13) ? 0.f : b11;
        acc += tdot(m00, m01, m10, m11, wC + wo);
    }
    // none
    acc += tdot(b00, b01, b10, b11, wD + wo);
    acc += w3[pos];

    l1out[gid] = acc;
    block_stats(acc, stats, 0, wls, wlss);
}

// Layer 2: one thread per (sample, 7x7 position). Applies BN1 affine on the fly.
__global__ void __launch_bounds__(256) k2(const float* __restrict__ l1buf,
                                          const float* __restrict__ w1,
                                          const float* __restrict__ w2,
                                          const float* __restrict__ w4,
                                          const float* __restrict__ gamma,
                                          const float* __restrict__ beta,
                                          double* __restrict__ stats,
                                          float* __restrict__ l2out) {
    __shared__ float wls[4], wlss[4];
    double mean = stats[0] * (1.0 / (double)N1);
    double var = stats[1] * (1.0 / (double)N1) - mean * mean;
    float a1 = (float)((double)gamma[0] / sqrt(var + 1e-5));
    float c1 = beta[0] - (float)mean * a1;

    int gid = blockIdx.x * 256 + threadIdx.x;
    int b = gid / 49;
    int pos = gid - b * 49;
    int i = pos / 7;
    int j = pos - i * 7;

    const float* hb = l1buf + b * 196;
    int r0 = (2 * i) * 14 + 2 * j;
    float2 tp = *(const float2*)(hb + r0);
    float2 bo = *(const float2*)(hb + r0 + 14);
    float h00 = a1 * tp.x + c1, h01 = a1 * tp.y + c1;
    float h10 = a1 * bo.x + c1, h11 = a1 * bo.y + c1;

    float acc = h00 * w1[r0] + h01 * w1[r0 + 1] + h10 * w1[r0 + 14] + h11 * w1[r0 + 15];
    acc += tdot(h00, h01, h10, h11, w2 + i * 70 + 10 * j);
    acc += w4[pos];

    l2out[gid] = acc;
    block_stats(acc, stats, 2, wls, wlss);
}

// FC: 4 lanes per sample split the 1225 (p<=q) pairs; shuffle-reduce; lane part==0 writes 10 outs.
__global__ void __launch_bounds__(256) k3(const float* __restrict__ l2buf,
                                          const float* __restrict__ wt12,
                                          const float* __restrict__ w_fc1,
                                          const float* __restrict__ b_fc1,
                                          const float* __restrict__ b_fc2,
                                          const float* __restrict__ gamma,
                                          const float* __restrict__ beta,
                                          const double* __restrict__ stats,
                                          float* __restrict__ out) {
    double mean = stats[2] * (1.0 / (double)N2);
    double var = stats[3] * (1.0 / (double)N2) - mean * mean;
    float a2 = (float)((double)gamma[0] / sqrt(var + 1e-5));
    float c2 = beta[0] - (float)mean * a2;

    __shared__ float vs[64 * 49];  // 64 samples per block, 12.25 KB
    int t = threadIdx.x;
    int sbase = blockIdx.x * 64;
    for (int k = t; k < 64 * 49; k += 256)
        vs[k] = a2 * l2buf[sbase * 49 + k] + c2;
    __syncthreads();

    int sloc = t >> 2;
    int part = t & 3;
    const float* v = vs + sloc * 49;

    float acc[10];
    #pragma unroll
    for (int o = 0; o < 10; ++o) acc[o] = 0.f;

    // FC1 partial: each part covers a k-range
    {
        int k0 = part * 13;
        int k1 = (k0 + 13 < 49) ? k0 + 13 : 49;
        for (int k = k0; k < k1; ++k) {
            float vk = v[k];
            #pragma unroll
            for (int o = 0; o < 10; ++o) acc[o] += vk * w_fc1[o * 49 + k];
        }
    }

    // FC2: pairs (p<=q), p strided by part
    for (int p = part; p < 49; p += 4) {
        float vp = v[p];
        const float* wrow = wt12 + (p * 49) * 12;
        for (int q = p; q < 49; ++q) {
            float pv = vp * v[q];
            const float* w = wrow + q * 12;
            float4 w0 = *(const float4*)(w);
            float4 w1v = *(const float4*)(w + 4);
            float2 w2v = *(const float2*)(w + 8);
            acc[0] += pv * w0.x;  acc[1] += pv * w0.y;
            acc[2] += pv * w0.z;  acc[3] += pv * w0.w;
            acc[4] += pv * w1v.x; acc[5] += pv * w1v.y;
            acc[6] += pv * w1v.z; acc[7] += pv * w1v.w;
            acc[8] += pv * w2v.x; acc[9] += pv * w2v.y;
        }
    }

    // reduce the 4 parts (adjacent lanes)
    #pragma unroll
    for (int o = 0; o < 10; ++o) {
        acc[o] += __shfl_xor(acc[o], 1);
        acc[o] += __shfl_xor(acc[o], 2);
    }

    if (part == 0) {
        int s = sbase + sloc;
        #pragma unroll
        for (int o = 0; o < 10; ++o)
            out[s * 10 + o] = acc[o] + b_fc1[o] + b_fc2[o];
    }
}

extern "C" void kernel_launch(void* const* d_in, const int* in_sizes, int n_in,
                              void* d_out, int out_size, void* d_ws, size_t ws_size,
                              hipStream_t stream) {
    const float* x      = (const float*)d_in[0];
    const float* l1_w1  = (const float*)d_in[1];
    const float* l1_w2_1 = (const float*)d_in[2];
    const float* l1_w2_2 = (const float*)d_in[3];
    const float* l1_w2_3 = (const float*)d_in[4];
    const float* l1_w2_4 = (const float*)d_in[5];
    const float* l1_w3  = (const float*)d_in[6];
    const float* l2_w1  = (const float*)d_in[7];
    const float* l2_w2  = (const float*)d_in[8];
    const float* l2_w4  = (const float*)d_in[9];
    const float* w_fc1  = (const float*)d_in[10];
    const float* b_fc1  = (const float*)d_in[11];
    const float* w_fc2  = (const float*)d_in[12];
    const float* b_fc2  = (const float*)d_in[13];
    const float* bn_gamma = (const float*)d_in[14];
    const float* bn_beta  = (const float*)d_in[15];

    char* ws = (char*)d_ws;
    double* stats = (double*)ws;
    float* wt12  = (float*)(ws + WS_WT12_OFF);
    float* l1buf = (float*)(ws + WS_L1_OFF);
    float* l2buf = (float*)(ws + WS_L2_OFF);
    float* out = (float*)d_out;

    hipMemsetAsync(stats, 0, 32, stream);
    ktranspose<<<10, 256, 0, stream>>>(w_fc2, wt12);
    k1<<<N1 / 256, 256, 0, stream>>>(x, l1_w1, l1_w2_1, l1_w2_2, l1_w2_3, l1_w2_4,
                                     l1_w3, l1buf, stats);
    k2<<<N2 / 256, 256, 0, stream>>>(l1buf, l2_w1, l2_w2, l2_w4, bn_gamma, bn_beta,
                                     stats, l2buf);
    k3<<<BATCH * 4 / 256, 256, 0, stream>>>(l2buf, wt12, w_fc1, b_fc1, b_fc2,
                                            bn_gamma, bn_beta, stats, out);
}

// Round 2
// 111.847 us; speedup vs baseline: 4.4188x; 4.4188x over previous
//
#include <hip/hip_runtime.h>

#define BATCH 16384
#define N1 (BATCH * 196)
#define N2 (BATCH * 49)

// ws layout (bytes):
//   [0,32)             : double stats[4] = {sum1, sumsq1, sum2, sumsq2}
//   [64, 115312)       : wt12  = w_fc2^T padded  [2401][12]
//   [115312, 127856)   : wk1   = per-pos fused L1 weights [196][16]
//   [127856, 130992)   : wk2   = per-pos fused L2 weights [49][16]
//   [130992, 133344)   : wfc1t = w_fc1^T padded  [49][12]
//   [133376, 12978432) : l1buf BATCH*196 floats
//   [12978432, ...)    : l2buf BATCH*49 floats
#define WS_WT12_OFF   64
#define WS_WK1_OFF    115312
#define WS_WK2_OFF    127856
#define WS_WFC1T_OFF  130992
#define WS_L1_OFF     133376
#define WS_L2_OFF     12978432

#define S1 16   // samples per k1 block
#define S2 8    // sample-groups per k2 block (4 samples each)

__device__ __forceinline__ void block_stats2(float s, float ss, double* stats, int idx,
                                             float* wls, float* wlss) {
    #pragma unroll
    for (int off = 32; off; off >>= 1) {
        s  += __shfl_down(s, off);
        ss += __shfl_down(ss, off);
    }
    int lane = threadIdx.x & 63, wid = threadIdx.x >> 6;
    if (lane == 0) { wls[wid] = s; wlss[wid] = ss; }
    __syncthreads();
    if (threadIdx.x == 0) {
        atomicAdd(&stats[idx],     (double)(wls[0] + wls[1] + wls[2] + wls[3]));
        atomicAdd(&stats[idx + 1], (double)(wlss[0] + wlss[1] + wlss[2] + wlss[3]));
    }
}

// One-time prep: transpose w_fc2 / w_fc1, fuse the 4 transform weight arrays
// (masks folded in) + pool + bias into per-position vectors.
__global__ void __launch_bounds__(256) kprep(
        const float* __restrict__ wf2, const float* __restrict__ wfc1,
        const float* __restrict__ l1w1, const float* __restrict__ wA,
        const float* __restrict__ wB, const float* __restrict__ wC,
        const float* __restrict__ wD, const float* __restrict__ l1w3,
        const float* __restrict__ l2w1, const float* __restrict__ l2w2,
        const float* __restrict__ l2w4,
        float* __restrict__ wt12, float* __restrict__ wk1,
        float* __restrict__ wk2, float* __restrict__ wfc1t) {
    int i = blockIdx.x * 256 + threadIdx.x;
    if (i < 2401) {
        #pragma unroll
        for (int o = 0; o < 10; ++o) wt12[i * 12 + o] = wf2[o * 2401 + i];
        wt12[i * 12 + 10] = 0.f;
        wt12[i * 12 + 11] = 0.f;
    }
    if (i < 196) {
        int pi = i / 14, pj = i - 14 * pi;
        int r0 = 2 * pi * 28 + 2 * pj;
        float* o = wk1 + i * 16;
        o[0] = l1w1[r0];      o[1] = l1w1[r0 + 1];
        o[2] = l1w1[r0 + 28]; o[3] = l1w1[r0 + 29];
        // element order: 00,01,10,11
        float mA[4] = { pj != 0 ? 1.f : 0.f, pj != 13 ? 1.f : 0.f,
                        pj != 0 ? 1.f : 0.f, pj != 13 ? 1.f : 0.f };   // left_right (cols)
        float mB[4] = { pi != 0 ? 1.f : 0.f, pi != 0 ? 1.f : 0.f,
                        pi != 13 ? 1.f : 0.f, pi != 13 ? 1.f : 0.f };  // top_bottom (rows)
        const int e1[10] = {0,1,2,3,0,0,0,1,1,2};
        const int e2[10] = {0,1,2,3,1,2,3,2,3,3};
        int wo = pi * 140 + 10 * pj;
        #pragma unroll
        for (int t = 0; t < 10; ++t) {
            float cA = mA[e1[t]] * mA[e2[t]];
            float cB = mB[e1[t]] * mB[e2[t]];
            o[4 + t] = wA[wo + t] * cA + wB[wo + t] * cB
                     + wC[wo + t] * cA * cB + wD[wo + t];
        }
        o[14] = l1w3[i];
        o[15] = 0.f;
    }
    if (i < 49) {
        int pi = i / 7, pj = i - 7 * pi;
        int r0 = 2 * pi * 14 + 2 * pj;
        float* o = wk2 + i * 16;
        o[0] = l2w1[r0];      o[1] = l2w1[r0 + 1];
        o[2] = l2w1[r0 + 14]; o[3] = l2w1[r0 + 15];
        #pragma unroll
        for (int t = 0; t < 10; ++t) o[4 + t] = l2w2[pi * 70 + 10 * pj + t];
        o[14] = l2w4[i];
        o[15] = 0.f;
        #pragma unroll
        for (int o2 = 0; o2 < 10; ++o2) wfc1t[i * 12 + o2] = wfc1[o2 * 49 + i];
        wfc1t[i * 12 + 10] = 0.f;
        wfc1t[i * 12 + 11] = 0.f;
    }
}

// Layer 1: lane = position (196 active of 256), loop over S1 samples.
// Weights live in 4 float4 registers for the whole loop.
__global__ void __launch_bounds__(256) k1(const float* __restrict__ x,
                                          const float* __restrict__ wk1,
                                          float* __restrict__ l1out,
                                          double* __restrict__ stats) {
    __shared__ float wls[4], wlss[4];
    int t = threadIdx.x;
    bool active = t < 196;
    int pos = active ? t : 0;
    int pi = pos / 14, pj = pos - 14 * pi;
    const float4* wp = (const float4*)(wk1 + pos * 16);
    float4 a0 = wp[0], a1 = wp[1], a2 = wp[2], a3 = wp[3];
    int r0 = (2 * pi) * 28 + 2 * pj;
    int sbase = blockIdx.x * S1;
    float sum = 0.f, sumsq = 0.f;
    #pragma unroll 4
    for (int s = 0; s < S1; ++s) {
        const float* xb = x + (size_t)(sbase + s) * 784;
        float2 tp = *(const float2*)(xb + r0);
        float2 bo = *(const float2*)(xb + r0 + 28);
        float b00 = tp.x, b01 = tp.y, b10 = bo.x, b11 = bo.y;
        float acc = b00 * a0.x + b01 * a0.y + b10 * a0.z + b11 * a0.w;
        acc += b00 * b00 * a1.x + b01 * b01 * a1.y + b10 * b10 * a1.z + b11 * b11 * a1.w;
        acc += b00 * b01 * a2.x + b00 * b10 * a2.y + b00 * b11 * a2.z + b01 * b10 * a2.w;
        acc += b01 * b11 * a3.x + b10 * b11 * a3.y + a3.z;
        if (active) {
            l1out[(size_t)(sbase + s) * 196 + pos] = acc;
            sum += acc;
            sumsq += acc * acc;
        }
    }
    block_stats2(sum, sumsq, stats, 0, wls, wlss);
}

// Layer 2: lanes = 4 samples x 49 positions (196 active), loop over S2 groups.
__global__ void __launch_bounds__(256) k2(const float* __restrict__ l1buf,
                                          const float* __restrict__ wk2,
                                          const float* __restrict__ gamma,
                                          const float* __restrict__ beta,
                                          double* __restrict__ stats,
                                          float* __restrict__ l2out) {
    __shared__ float wls[4], wlss[4];
    double mean = stats[0] * (1.0 / (double)N1);
    double var  = stats[1] * (1.0 / (double)N1) - mean * mean;
    float a1 = (float)((double)gamma[0] / sqrt(var + 1e-5));
    float c1 = beta[0] - (float)mean * a1;

    int t = threadIdx.x;
    bool active = t < 196;
    int tt = active ? t : 0;
    int sub = tt / 49;
    int pos = tt - 49 * sub;
    int pi = pos / 7, pj = pos - 7 * pi;
    const float4* wp = (const float4*)(wk2 + pos * 16);
    float4 a0 = wp[0], q1 = wp[1], q2 = wp[2], q3 = wp[3];
    int r0 = (2 * pi) * 14 + 2 * pj;
    int sbase = blockIdx.x * (4 * S2);
    float sum = 0.f, sumsq = 0.f;
    #pragma unroll 4
    for (int s = 0; s < S2; ++s) {
        int smp = sbase + s * 4 + sub;
        const float* hb = l1buf + (size_t)smp * 196;
        float2 tp = *(const float2*)(hb + r0);
        float2 bo = *(const float2*)(hb + r0 + 14);
        float h00 = a1 * tp.x + c1, h01 = a1 * tp.y + c1;
        float h10 = a1 * bo.x + c1, h11 = a1 * bo.y + c1;
        float acc = h00 * a0.x + h01 * a0.y + h10 * a0.z + h11 * a0.w;
        acc += h00 * h00 * q1.x + h01 * h01 * q1.y + h10 * h10 * q1.z + h11 * h11 * q1.w;
        acc += h00 * h01 * q2.x + h00 * h10 * q2.y + h00 * h11 * q2.z + h01 * h10 * q2.w;
        acc += h01 * h11 * q3.x + h10 * h11 * q3.y + q3.z;
        if (active) {
            l2out[(size_t)smp * 49 + pos] = acc;
            sum += acc;
            sumsq += acc * acc;
        }
    }
    block_stats2(sum, sumsq, stats, 2, wls, wlss);
}

// FC: block = 512 threads = 8 part-waves x 64 samples. lane = sample, so
// (p,q) pair indices are wave-uniform -> weight loads become scalar loads.
__global__ void __launch_bounds__(512) k3(const float* __restrict__ l2buf,
                                          const float* __restrict__ wt12,
                                          const float* __restrict__ wfc1t,
                                          const float* __restrict__ b_fc1,
                                          const float* __restrict__ b_fc2,
                                          const float* __restrict__ gamma,
                                          const float* __restrict__ beta,
                                          const double* __restrict__ stats,
                                          float* __restrict__ out) {
    __shared__ float vs[64 * 51];        // stride 51: gcd(51 mod 32, 32)=1 -> conflict-free
    __shared__ float part[8][64][10];
    double mean = stats[2] * (1.0 / (double)N2);
    double var  = stats[3] * (1.0 / (double)N2) - mean * mean;
    float a2 = (float)((double)gamma[0] / sqrt(var + 1e-5));
    float c2 = beta[0] - (float)mean * a2;

    int t = threadIdx.x;
    int sbase = blockIdx.x * 64;
    for (int idx = t; idx < 64 * 49; idx += 512) {
        int sl = idx / 49, k = idx - 49 * sl;
        vs[sl * 51 + k] = a2 * l2buf[(size_t)(sbase + sl) * 49 + k] + c2;
    }
    __syncthreads();

    int lane = t & 63;   // sample
    int wid  = t >> 6;   // part 0..7
    const float* v = vs + lane * 51;

    float acc[10];
    #pragma unroll
    for (int o = 0; o < 10; ++o) acc[o] = 0.f;

    // FC1: k strided across parts (uniform k per wave -> scalar weight loads)
    for (int k = wid; k < 49; k += 8) {
        float vk = v[k];
        const float* w = wfc1t + k * 12;
        #pragma unroll
        for (int o = 0; o < 10; ++o) acc[o] += vk * w[o];
    }

    // FC2: p strided across parts; (p,q) uniform per wave
    for (int p = wid; p < 49; p += 8) {
        float vp = v[p];
        const float* wrow = wt12 + (size_t)(p * 49) * 12;
        #pragma unroll 4
        for (int q = p; q < 49; ++q) {
            float pv = vp * v[q];
            const float* w = wrow + q * 12;
            #pragma unroll
            for (int o = 0; o < 10; ++o) acc[o] += pv * w[o];
        }
    }

    #pragma unroll
    for (int o = 0; o < 10; ++o) part[wid][lane][o] = acc[o];
    __syncthreads();

    for (int idx = t; idx < 640; idx += 512) {
        int sl = idx / 10, o = idx - 10 * sl;
        float s = part[0][sl][o] + part[1][sl][o] + part[2][sl][o] + part[3][sl][o]
                + part[4][sl][o] + part[5][sl][o] + part[6][sl][o] + part[7][sl][o];
        out[(size_t)(sbase + sl) * 10 + o] = s + b_fc1[o] + b_fc2[o];
    }
}

extern "C" void kernel_launch(void* const* d_in, const int* in_sizes, int n_in,
                              void* d_out, int out_size, void* d_ws, size_t ws_size,
                              hipStream_t stream) {
    const float* x       = (const float*)d_in[0];
    const float* l1_w1   = (const float*)d_in[1];
    const float* l1_w2_1 = (const float*)d_in[2];
    const float* l1_w2_2 = (const float*)d_in[3];
    const float* l1_w2_3 = (const float*)d_in[4];
    const float* l1_w2_4 = (const float*)d_in[5];
    const float* l1_w3   = (const float*)d_in[6];
    const float* l2_w1   = (const float*)d_in[7];
    const float* l2_w2   = (const float*)d_in[8];
    const float* l2_w4   = (const float*)d_in[9];
    const float* w_fc1   = (const float*)d_in[10];
    const float* b_fc1   = (const float*)d_in[11];
    const float* w_fc2   = (const float*)d_in[12];
    const float* b_fc2   = (const float*)d_in[13];
    const float* bn_gamma = (const float*)d_in[14];
    const float* bn_beta  = (const float*)d_in[15];

    char* ws = (char*)d_ws;
    double* stats = (double*)ws;
    float* wt12   = (float*)(ws + WS_WT12_OFF);
    float* wk1    = (float*)(ws + WS_WK1_OFF);
    float* wk2    = (float*)(ws + WS_WK2_OFF);
    float* wfc1t  = (float*)(ws + WS_WFC1T_OFF);
    float* l1buf  = (float*)(ws + WS_L1_OFF);
    float* l2buf  = (float*)(ws + WS_L2_OFF);
    float* out = (float*)d_out;

    hipMemsetAsync(stats, 0, 32, stream);
    kprep<<<10, 256, 0, stream>>>(w_fc2, w_fc1, l1_w1, l1_w2_1, l1_w2_2, l1_w2_3,
                                  l1_w2_4, l1_w3, l2_w1, l2_w2, l2_w4,
                                  wt12, wk1, wk2, wfc1t);
    k1<<<BATCH / S1, 256, 0, stream>>>(x, wk1, l1buf, stats);
    k2<<<BATCH / (4 * S2), 256, 0, stream>>>(l1buf, wk2, bn_gamma, bn_beta, stats, l2buf);
    k3<<<BATCH / 64, 512, 0, stream>>>(l2buf, wt12, wfc1t, b_fc1, b_fc2,
                                       bn_gamma, bn_beta, stats, out);
}